// Round 4
// baseline (2011.561 us; speedup 1.0000x reference)
//
#include <hip/hip_runtime.h>
#include <hip/hip_bf16.h>

static __device__ __forceinline__ float lrelu01(float v) { return v > 0.0f ? v : 0.01f * v; }

static __device__ __forceinline__ float dot4(const float4 a, const float4 b, float acc) {
  acc = fmaf(a.x, b.x, acc);
  acc = fmaf(a.y, b.y, acc);
  acc = fmaf(a.z, b.z, acc);
  acc = fmaf(a.w, b.w, acc);
  return acc;
}

// ---------------- K_proj: 5 feature projections -> h0[N][160] ----------------
// grid = (ceil(n/32), 4). y=0: small segs (din 6 + 11), thread-per-node.
// y=1..3: big segs (din 768): wave = 4 groups x 16 lanes, 2 nodes per lane-group.
__global__ __launch_bounds__(256) void k_proj(
    const float* __restrict__ pre_x,
    const float* __restrict__ num_prop,
    const float* __restrict__ num_cat,
    const float* __restrict__ des,
    const float* __restrict__ tweet,
    const float* __restrict__ w_np, const float* __restrict__ b_np,
    const float* __restrict__ w_nc, const float* __restrict__ b_nc,
    const float* __restrict__ w_des, const float* __restrict__ b_des,
    const float* __restrict__ w_text, const float* __restrict__ b_text,
    const float* __restrict__ w_tw, const float* __restrict__ b_tw,
    float* __restrict__ h0, int n)
{
  const int seg = blockIdx.y;
  if (seg == 0) {
    // small projections: thread-per-node (tiny data, weights wave-uniform -> scalar)
    const int node = blockIdx.x * 256 + threadIdx.x;
    if (node >= n) return;
    float* o = h0 + (size_t)node * 160;
    {
      const float* xr = num_prop + (size_t)node * 6;
      float xv[6];
      #pragma unroll
      for (int k = 0; k < 6; ++k) xv[k] = xr[k];
      #pragma unroll
      for (int c = 0; c < 32; ++c) {
        float s = b_np[c];
        #pragma unroll
        for (int k = 0; k < 6; ++k) s = fmaf(xv[k], w_np[c * 6 + k], s);
        o[c] = lrelu01(s);
      }
    }
    {
      const float* xr = num_cat + (size_t)node * 11;
      float xv[11];
      #pragma unroll
      for (int k = 0; k < 11; ++k) xv[k] = xr[k];
      #pragma unroll
      for (int c = 0; c < 32; ++c) {
        float s = b_nc[c];
        #pragma unroll
        for (int k = 0; k < 11; ++k) s = fmaf(xv[k], w_nc[c * 11 + k], s);
        o[32 + c] = lrelu01(s);
      }
    }
    return;
  }

  const float* x; const float* w; const float* b; int coff;
  if (seg == 1)      { x = des;   w = w_des;  b = b_des;  coff = 64;  }
  else if (seg == 2) { x = tweet; w = w_text; b = b_text; coff = 96;  }
  else               { x = pre_x; w = w_tw;   b = b_tw;   coff = 128; }

  const int t = threadIdx.x;
  const int wave = t >> 6;
  const int lane = t & 63;
  const int grp  = lane >> 4;
  const int kl   = lane & 15;

  const int node0 = blockIdx.x * 32 + wave * 8 + grp * 2;
  const int node1 = node0 + 1;
  const bool ok0 = node0 < n, ok1 = node1 < n;
  const int m0 = ok0 ? node0 : 0;
  const int m1 = ok1 ? node1 : 0;

  // 768 floats = 192 float4 per row; lane kl covers float4 idx kl + 16j (j=0..11)
  const float4* x0 = reinterpret_cast<const float4*>(x) + (size_t)m0 * 192 + kl;
  const float4* x1 = reinterpret_cast<const float4*>(x) + (size_t)m1 * 192 + kl;
  const float4* wr = reinterpret_cast<const float4*>(w) + kl;

  float a0[32], a1[32];
  #pragma unroll
  for (int c = 0; c < 32; ++c) { a0[c] = 0.0f; a1[c] = 0.0f; }

  for (int j = 0; j < 12; ++j) {
    const float4 xa = x0[j * 16];
    const float4 xb = x1[j * 16];
    const float4* wj = wr + j * 16;
    #pragma unroll
    for (int c = 0; c < 32; ++c) {
      const float4 wv = wj[(size_t)c * 192];
      a0[c] = dot4(xa, wv, a0[c]);
      a1[c] = dot4(xb, wv, a1[c]);
    }
  }

  // 16-lane butterfly; channel c lands on lane kl == (c & 15), slot c>>4
  float v00 = 0.f, v01 = 0.f, v10 = 0.f, v11 = 0.f;
  #pragma unroll
  for (int c = 0; c < 32; ++c) {
    float r0 = a0[c], r1 = a1[c];
    r0 += __shfl_xor(r0, 1); r0 += __shfl_xor(r0, 2); r0 += __shfl_xor(r0, 4); r0 += __shfl_xor(r0, 8);
    r1 += __shfl_xor(r1, 1); r1 += __shfl_xor(r1, 2); r1 += __shfl_xor(r1, 4); r1 += __shfl_xor(r1, 8);
    if (kl == (c & 15)) {
      if (c < 16) { v00 = r0; v10 = r1; }
      else        { v01 = r0; v11 = r1; }
    }
  }

  const float bl = b[kl], bh = b[kl + 16];
  if (ok0) {
    h0[(size_t)node0 * 160 + coff + kl]      = lrelu01(v00 + bl);
    h0[(size_t)node0 * 160 + coff + 16 + kl] = lrelu01(v01 + bh);
  }
  if (ok1) {
    h0[(size_t)node1 * 160 + coff + kl]      = lrelu01(v10 + bl);
    h0[(size_t)node1 * 160 + coff + 16 + kl] = lrelu01(v11 + bh);
  }
}

// ---------------- [n,160] x [dout,160]^T, 32-col segment per blockIdx.y ----------------
// wave = 4 nodes x 16 lanes; lane kl covers float4 idx {kl, kl+16, kl+32 (kl<8)}
__global__ __launch_bounds__(256) void k_lin160(
    const float* __restrict__ x, const float* __restrict__ w,
    const float* __restrict__ bias, float* __restrict__ out,
    int n, int act)
{
  const int t = threadIdx.x;
  const int wave = t >> 6, lane = t & 63, grp = lane >> 4, kl = lane & 15;
  const int node = blockIdx.x * 16 + wave * 4 + grp;
  if (node >= n) return;
  const int seg = blockIdx.y;
  const bool tail = kl < 8;

  const float4* xr = reinterpret_cast<const float4*>(x) + (size_t)node * 40 + kl;
  const float4* wr = reinterpret_cast<const float4*>(w) + (size_t)seg * 32 * 40 + kl;

  const float4 xv0 = xr[0];
  const float4 xv1 = xr[16];
  float4 xv2 = {0.f, 0.f, 0.f, 0.f};
  if (tail) xv2 = xr[32];

  float acc[32];
  #pragma unroll
  for (int c = 0; c < 32; ++c) {
    float s = dot4(xv0, wr[(size_t)c * 40], 0.0f);
    s = dot4(xv1, wr[(size_t)c * 40 + 16], s);
    if (tail) s = dot4(xv2, wr[(size_t)c * 40 + 32], s);
    acc[c] = s;
  }

  float v0 = 0.f, v1 = 0.f;
  #pragma unroll
  for (int c = 0; c < 32; ++c) {
    float r = acc[c];
    r += __shfl_xor(r, 1); r += __shfl_xor(r, 2); r += __shfl_xor(r, 4); r += __shfl_xor(r, 8);
    if (kl == (c & 15)) { if (c < 16) v0 = r; else v1 = r; }
  }

  if (bias) { v0 += bias[seg * 32 + kl]; v1 += bias[seg * 32 + 16 + kl]; }
  if (act) { v0 = lrelu01(v0); v1 = lrelu01(v1); }
  out[(size_t)node * 160 + seg * 32 + kl]      = v0;
  out[(size_t)node * 160 + seg * 32 + 16 + kl] = v1;
}

// ---------------- per-node attention dots ----------------
__global__ __launch_bounds__(256) void k_att(
    const float* __restrict__ h, const float* __restrict__ att_s,
    const float* __restrict__ att_d,
    float* __restrict__ a_s, float* __restrict__ a_d, int n)
{
  const int t = threadIdx.x;
  const int wave = t >> 6, lane = t & 63, grp = lane >> 4, kl = lane & 15;
  const int node = blockIdx.x * 16 + wave * 4 + grp;
  if (node >= n) return;
  const bool tail = kl < 8;

  const float4* xr = reinterpret_cast<const float4*>(h) + (size_t)node * 40 + kl;
  const float4* as4 = reinterpret_cast<const float4*>(att_s) + kl;
  const float4* ad4 = reinterpret_cast<const float4*>(att_d) + kl;

  const float4 x0 = xr[0];
  const float4 x1 = xr[16];
  float s = dot4(x0, as4[0], 0.0f);  s = dot4(x1, as4[16], s);
  float d = dot4(x0, ad4[0], 0.0f);  d = dot4(x1, ad4[16], d);
  if (tail) {
    const float4 x2 = xr[32];
    s = dot4(x2, as4[32], s);
    d = dot4(x2, ad4[32], d);
  }
  s += __shfl_xor(s, 1); s += __shfl_xor(s, 2); s += __shfl_xor(s, 4); s += __shfl_xor(s, 8);
  d += __shfl_xor(d, 1); d += __shfl_xor(d, 2); d += __shfl_xor(d, 4); d += __shfl_xor(d, 8);
  if (kl == 0) { a_s[node] = s; a_d[node] = d; }
}

// ---------------- CSR build (graph static; built once, reused both layers) ----
__global__ __launch_bounds__(256) void k_initdeg(int* __restrict__ deg, int n)
{
  const int i = blockIdx.x * 256 + threadIdx.x;
  if (i < n) deg[i] = 1;   // self-loop
}

__global__ __launch_bounds__(256) void k_count(
    const int* __restrict__ ei, int e, int* __restrict__ deg)
{
  const int i = blockIdx.x * 256 + threadIdx.x;
  if (i < e) atomicAdd(deg + ei[e + i], 1);
}

__global__ __launch_bounds__(256) void k_scan(
    const int* __restrict__ deg, int* __restrict__ row_start,
    int* __restrict__ cursor, int n)
{
  __shared__ int part[256];
  const int t = threadIdx.x;
  const int chunk = (n + 255) / 256;
  const int lo = t * chunk;
  const int hi = min(lo + chunk, n);
  int s = 0;
  for (int i = lo; i < hi; ++i) s += deg[i];
  part[t] = s;
  __syncthreads();
  for (int off = 1; off < 256; off <<= 1) {
    int v = (t >= off) ? part[t - off] : 0;
    __syncthreads();
    part[t] += v;
    __syncthreads();
  }
  int base = (t == 0) ? 0 : part[t - 1];
  for (int i = lo; i < hi; ++i) {
    row_start[i] = base;
    cursor[i] = base;
    base += deg[i];
  }
  if (t == 0) row_start[n] = part[255];
}

__global__ __launch_bounds__(256) void k_scatter(
    const int* __restrict__ ei, int e, int n,
    int* __restrict__ cursor, int* __restrict__ csr_src)
{
  const int i = blockIdx.x * 256 + threadIdx.x;
  const int total = e + n;
  if (i >= total) return;
  int s, d;
  if (i < e) { s = ei[i]; d = ei[e + i]; }
  else       { s = i - e; d = s; }
  const int slot = atomicAdd(cursor + d, 1);
  csr_src[slot] = s;
}

// ---------------- gather: one 64-lane wave per destination node ----------------
// lanes 0..39 each own one float4 of the 160-ch row -> 1 dwordx4 per src row.
__global__ __launch_bounds__(256) void k_gather(
    const int* __restrict__ row_start, const int* __restrict__ csr_src,
    const float* __restrict__ h, const float* __restrict__ a_s,
    const float* __restrict__ a_d, const float* __restrict__ bias,
    float* __restrict__ out, int n)
{
  const int d = blockIdx.x * 4 + (threadIdx.x >> 6);
  if (d >= n) return;                       // wave-uniform
  const int lane = threadIdx.x & 63;
  const int beg = row_start[d];
  const int end = row_start[d + 1];
  const float ad = a_d[d];
  const bool act = lane < 40;
  const float4* h4 = reinterpret_cast<const float4*>(h);

  float z = 0.0f;
  float4 acc = {0.f, 0.f, 0.f, 0.f};

  for (int s = beg; s < end; ++s) {
    const int src = csr_src[s];             // broadcast load
    float e = a_s[src] + ad;                // broadcast load
    e = e > 0.0f ? e : 0.2f * e;            // negative_slope = 0.2
    const float ex = __expf(e);             // shift-invariant: segment_max skipped
    z += ex;
    if (act) {
      const float4 hv = h4[(size_t)src * 40 + lane];
      acc.x = fmaf(ex, hv.x, acc.x);
      acc.y = fmaf(ex, hv.y, acc.y);
      acc.z = fmaf(ex, hv.z, acc.z);
      acc.w = fmaf(ex, hv.w, acc.w);
    }
  }

  const float inv = 1.0f / (z + 1e-16f);
  if (act) {
    const float4 b4 = reinterpret_cast<const float4*>(bias)[lane];
    float4 o;
    o.x = fmaf(acc.x, inv, b4.x);
    o.y = fmaf(acc.y, inv, b4.y);
    o.z = fmaf(acc.z, inv, b4.z);
    o.w = fmaf(acc.w, inv, b4.w);
    reinterpret_cast<float4*>(out)[(size_t)d * 40 + lane] = o;
  }
}

// ---------------- head: em = lrelu(h @ w_o1^T + b_o1); out = em @ w_o2^T + b_o2 ----------------
__global__ __launch_bounds__(256) void k_out(
    const float* __restrict__ h,
    const float* __restrict__ w1, const float* __restrict__ b1,
    const float* __restrict__ w2, const float* __restrict__ b2,
    float* __restrict__ out2, float* __restrict__ em, int n)
{
  const int t = threadIdx.x;
  const int wave = t >> 6, lane = t & 63, grp = lane >> 4, kl = lane & 15;
  const int node = blockIdx.x * 16 + wave * 4 + grp;
  if (node >= n) return;
  const bool tail = kl < 8;

  const float4* xr = reinterpret_cast<const float4*>(h) + (size_t)node * 40 + kl;
  const float4* wr = reinterpret_cast<const float4*>(w1) + kl;

  const float4 xv0 = xr[0];
  const float4 xv1 = xr[16];
  float4 xv2 = {0.f, 0.f, 0.f, 0.f};
  if (tail) xv2 = xr[32];

  float acc[80];
  #pragma unroll
  for (int c = 0; c < 80; ++c) {
    float s = dot4(xv0, wr[(size_t)c * 40], 0.0f);
    s = dot4(xv1, wr[(size_t)c * 40 + 16], s);
    if (tail) s = dot4(xv2, wr[(size_t)c * 40 + 32], s);
    acc[c] = s;
  }

  // butterfly; channel c -> lane (c & 15), slot c>>4 (5 slots: 80 = 5*16)
  float e0 = 0.f, e1 = 0.f, e2 = 0.f, e3 = 0.f, e4 = 0.f;
  #pragma unroll
  for (int c = 0; c < 80; ++c) {
    float r = acc[c];
    r += __shfl_xor(r, 1); r += __shfl_xor(r, 2); r += __shfl_xor(r, 4); r += __shfl_xor(r, 8);
    if (kl == (c & 15)) {
      const int slot = c >> 4;
      if (slot == 0) e0 = r;
      else if (slot == 1) e1 = r;
      else if (slot == 2) e2 = r;
      else if (slot == 3) e3 = r;
      else e4 = r;
    }
  }

  e0 = lrelu01(e0 + b1[kl]);
  e1 = lrelu01(e1 + b1[kl + 16]);
  e2 = lrelu01(e2 + b1[kl + 32]);
  e3 = lrelu01(e3 + b1[kl + 48]);
  e4 = lrelu01(e4 + b1[kl + 64]);

  float* emr = em + (size_t)node * 80;
  emr[kl]      = e0;
  emr[kl + 16] = e1;
  emr[kl + 32] = e2;
  emr[kl + 48] = e3;
  emr[kl + 64] = e4;

  float p0 = e0 * w2[kl] + e1 * w2[kl + 16] + e2 * w2[kl + 32]
           + e3 * w2[kl + 48] + e4 * w2[kl + 64];
  float p1 = e0 * w2[80 + kl] + e1 * w2[80 + kl + 16] + e2 * w2[80 + kl + 32]
           + e3 * w2[80 + kl + 48] + e4 * w2[80 + kl + 64];
  p0 += __shfl_xor(p0, 1); p0 += __shfl_xor(p0, 2); p0 += __shfl_xor(p0, 4); p0 += __shfl_xor(p0, 8);
  p1 += __shfl_xor(p1, 1); p1 += __shfl_xor(p1, 2); p1 += __shfl_xor(p1, 4); p1 += __shfl_xor(p1, 8);
  if (kl == 0) {
    out2[(size_t)node * 2 + 0] = p0 + b2[0];
    out2[(size_t)node * 2 + 1] = p1 + b2[1];
  }
}

extern "C" void kernel_launch(void* const* d_in, const int* in_sizes, int n_in,
                              void* d_out, int out_size, void* d_ws, size_t ws_size,
                              hipStream_t stream)
{
  const float* pre_x    = (const float*)d_in[0];
  const float* num_prop = (const float*)d_in[2];
  const float* num_cat  = (const float*)d_in[3];
  const float* des      = (const float*)d_in[4];
  const float* tweet    = (const float*)d_in[5];
  const int*   ei       = (const int*)d_in[6];
  const float* w_np  = (const float*)d_in[8];  const float* b_np  = (const float*)d_in[9];
  const float* w_nc  = (const float*)d_in[10]; const float* b_nc  = (const float*)d_in[11];
  const float* w_des = (const float*)d_in[12]; const float* b_des = (const float*)d_in[13];
  const float* w_text= (const float*)d_in[14]; const float* b_text= (const float*)d_in[15];
  const float* w_tw  = (const float*)d_in[16]; const float* b_tw  = (const float*)d_in[17];
  const float* w_in  = (const float*)d_in[18]; const float* b_in  = (const float*)d_in[19];
  const float* W1    = (const float*)d_in[20]; const float* b1    = (const float*)d_in[21];
  const float* as1   = (const float*)d_in[22]; const float* ad1   = (const float*)d_in[23];
  const float* W2    = (const float*)d_in[24]; const float* b2    = (const float*)d_in[25];
  const float* as2   = (const float*)d_in[26]; const float* ad2   = (const float*)d_in[27];
  const float* w_o1  = (const float*)d_in[28]; const float* b_o1  = (const float*)d_in[29];
  const float* w_o2  = (const float*)d_in[30]; const float* b_o2  = (const float*)d_in[31];

  const int n = in_sizes[2] / 6;     // num_prop is [N,6]
  const int e = in_sizes[7];         // edge_type is [E]

  float* buf0 = (float*)d_ws;                       // N*160
  float* buf1 = buf0 + (size_t)n * 160;             // N*160
  float* asb  = buf1 + (size_t)n * 160;             // N
  float* adb  = asb + n;                            // N
  int*   deg       = (int*)(adb + n);               // N
  int*   row_start = deg + n;                       // N+1
  int*   cursor    = row_start + (n + 1);           // N
  int*   csr_src   = cursor + n;                    // E+N

  const int nb   = (n + 255) / 256;
  const int nb32 = (n + 31) / 32;
  const int nb16 = (n + 15) / 16;
  const int eb = (e + 255) / 256;
  const int tb = (e + n + 255) / 256;
  const int gb = (n + 3) / 4;

  // ---- CSR build ----
  k_initdeg<<<nb, 256, 0, stream>>>(deg, n);
  k_count<<<eb, 256, 0, stream>>>(ei, e, deg);
  k_scan<<<1, 256, 0, stream>>>(deg, row_start, cursor, n);
  k_scatter<<<tb, 256, 0, stream>>>(ei, e, n, cursor, csr_src);

  // ---- features -> h0 (buf0) -> input linear -> hA (buf1) ----
  k_proj<<<dim3(nb32, 4), 256, 0, stream>>>(pre_x, num_prop, num_cat, des, tweet,
      w_np, b_np, w_nc, b_nc, w_des, b_des, w_text, b_text, w_tw, b_tw, buf0, n);
  k_lin160<<<dim3(nb16, 5), 256, 0, stream>>>(buf0, w_in, b_in, buf1, n, 1);

  // ---- GAT layer 1 ----
  k_lin160<<<dim3(nb16, 5), 256, 0, stream>>>(buf1, W1, nullptr, buf0, n, 0);
  k_att<<<nb16, 256, 0, stream>>>(buf0, as1, ad1, asb, adb, n);
  k_gather<<<gb, 256, 0, stream>>>(row_start, csr_src, buf0, asb, adb, b1, buf1, n);

  // ---- GAT layer 2 ----
  k_lin160<<<dim3(nb16, 5), 256, 0, stream>>>(buf1, W2, nullptr, buf0, n, 0);
  k_att<<<nb16, 256, 0, stream>>>(buf0, as2, ad2, asb, adb, n);
  k_gather<<<gb, 256, 0, stream>>>(row_start, csr_src, buf0, asb, adb, b2, buf1, n);

  // ---- head ----
  float* out2 = (float*)d_out;
  float* em   = out2 + (size_t)n * 2;
  k_out<<<nb16, 256, 0, stream>>>(buf1, w_o1, b_o1, w_o2, b_o2, out2, em, n);
}